// Round 6
// baseline (611.286 us; speedup 1.0000x reference)
//
#include <hip/hip_runtime.h>

#define NUM_USERS 50000
#define NUM_ITEMS 50000
#define N_NODES   100000
#define NNZ       3200000
#define EMB_DIM   64
#define N_LAYERS  3
#define BATCH     16384

#define NBUCK 512
#define ABITS 8                  // bucket = key >> 8 (256 nodes/bucket, 391 used)
#define NODES_PER_BUCK 256
#define TILE_EDGES 8192
#define NBUCK_BLOCKS ((N_NODES + NODES_PER_BUCK - 1) / NODES_PER_BUCK)   // 391

typedef unsigned long long ull;

// rec layout: src(17) | dst(17)<<17 | (val_bits>>2)<<34  (drops 2 mantissa bits)

// init: bufA = acc = concat(user_emb, item_emb), vectorized float4
__global__ void init_emb_kernel(const float* __restrict__ ue,
                                const float* __restrict__ ie,
                                float* __restrict__ bufA,
                                float* __restrict__ acc) {
    int idx = blockIdx.x * blockDim.x + threadIdx.x;
    const int total = N_NODES * (EMB_DIM / 4);
    if (idx >= total) return;
    const int uoff = NUM_USERS * (EMB_DIM / 4);
    float4 v;
    if (idx < uoff) v = ((const float4*)ue)[idx];
    else            v = ((const float4*)ie)[idx - uoff];
    ((float4*)bufA)[idx] = v;
    ((float4*)acc)[idx]  = v;
}

// coarse histogram of src>>8
__global__ void hist_src_kernel(const int* __restrict__ es, int* __restrict__ srcCnt) {
    __shared__ int h[NBUCK];
    int tid = threadIdx.x;
    int e0 = blockIdx.x * TILE_EDGES;
    for (int i = tid; i < NBUCK; i += 256) h[i] = 0;
    __syncthreads();
    for (int i = tid; i < TILE_EDGES; i += 256) {
        int e = e0 + i;
        if (e < NNZ) atomicAdd(&h[((unsigned)es[e]) >> ABITS], 1);
    }
    __syncthreads();
    for (int i = tid; i < NBUCK; i += 256) {
        int c = h[i];
        if (c) atomicAdd(&srcCnt[i], c);
    }
}

// single-block exclusive scan of 512 counts -> start (+cursor copy), sentinel at [512]
__global__ void scan512_kernel(const int* __restrict__ cnt,
                               int* __restrict__ start,
                               int* __restrict__ cursor) {
    __shared__ int sm[NBUCK];
    int t = threadIdx.x;          // 512
    int v = cnt[t];
    sm[t] = v;
    __syncthreads();
    for (int o = 1; o < NBUCK; o <<= 1) {
        int add = (t >= o) ? sm[t - o] : 0;
        __syncthreads();
        sm[t] += add;
        __syncthreads();
    }
    int excl = sm[t] - v;
    start[t]  = excl;
    cursor[t] = excl;
    if (t == NBUCK - 1) start[NBUCK] = NNZ;
}

// pass 0: partition edges by src>>8 into packed records; fused dst histogram
__global__ void srcPart_kernel(const float* __restrict__ ev,
                               const int*  __restrict__ es,
                               const int*  __restrict__ ed,
                               int* __restrict__ srcCursor,
                               int* __restrict__ dstCnt,
                               ull* __restrict__ tmpS) {
    __shared__ int hist[NBUCK];
    __shared__ int base[NBUCK];
    __shared__ int cnt2[NBUCK];
    __shared__ int hd[NBUCK];
    int tid = threadIdx.x;
    int e0 = blockIdx.x * TILE_EDGES;

    for (int i = tid; i < NBUCK; i += 256) { hist[i] = 0; hd[i] = 0; }
    __syncthreads();
    for (int i = tid; i < TILE_EDGES; i += 256) {
        int e = e0 + i;
        if (e < NNZ) atomicAdd(&hist[((unsigned)es[e]) >> ABITS], 1);
    }
    __syncthreads();
    for (int i = tid; i < NBUCK; i += 256) {
        int c = hist[i];
        base[i] = c ? atomicAdd(&srcCursor[i], c) : 0;
        cnt2[i] = 0;
    }
    __syncthreads();
    for (int i = tid; i < TILE_EDGES; i += 256) {
        int e = e0 + i;
        if (e >= NNZ) continue;
        int s = es[e], d = ed[e];
        atomicAdd(&hd[((unsigned)d) >> ABITS], 1);
        int b = ((unsigned)s) >> ABITS;
        int pos = base[b] + atomicAdd(&cnt2[b], 1);
        ull rec = (ull)(unsigned)s
                | ((ull)(unsigned)d << 17)
                | ((ull)(((unsigned)__float_as_int(ev[e])) >> 2) << 34);
        tmpS[pos] = rec;
    }
    __syncthreads();
    for (int i = tid; i < NBUCK; i += 256) {
        int c = hd[i];
        if (c) atomicAdd(&dstCnt[i], c);
    }
}

// pass A: partition (src-ordered) records by dst>>8 — coarse src order survives
__global__ void partA_kernel(const ull* __restrict__ tmpS,
                             int* __restrict__ dstCursor,
                             ull* __restrict__ tmp) {
    __shared__ int hist[NBUCK];
    __shared__ int base[NBUCK];
    __shared__ int cnt2[NBUCK];
    int tid = threadIdx.x;
    int e0 = blockIdx.x * TILE_EDGES;

    for (int i = tid; i < NBUCK; i += 256) hist[i] = 0;
    __syncthreads();
    for (int i = tid; i < TILE_EDGES; i += 256) {
        int e = e0 + i;
        if (e < NNZ) atomicAdd(&hist[(int)((tmpS[e] >> 25) & 0x1FF)], 1);
    }
    __syncthreads();
    for (int i = tid; i < NBUCK; i += 256) {
        int c = hist[i];
        base[i] = c ? atomicAdd(&dstCursor[i], c) : 0;
        cnt2[i] = 0;
    }
    __syncthreads();
    for (int i = tid; i < TILE_EDGES; i += 256) {
        int e = e0 + i;
        if (e >= NNZ) continue;
        ull rec = tmpS[e];
        int b = (int)((rec >> 25) & 0x1FF);
        int pos = base[b] + atomicAdd(&cnt2[b], 1);
        tmp[pos] = rec;
    }
}

// pass B: per bucket — node degrees + rowStart via LDS scan, then scatter to CSR
__global__ void partB_kernel(const ull* __restrict__ tmp,
                             const int* __restrict__ dstStart,
                             int* __restrict__ rowStart,
                             int* __restrict__ deg,
                             int2* __restrict__ sorted) {
    __shared__ int cnt[NODES_PER_BUCK];
    __shared__ int sc[NODES_PER_BUCK];
    __shared__ int cur[NODES_PER_BUCK];
    int b = blockIdx.x;
    int tid = threadIdx.x;           // 1024
    int nodeLo = b << ABITS;
    int startE = dstStart[b];
    int endE   = dstStart[b + 1];

    if (tid < NODES_PER_BUCK) cnt[tid] = 0;
    __syncthreads();
    for (int i = startE + tid; i < endE; i += 1024) {
        ull rec = tmp[i];
        atomicAdd(&cnt[(int)((rec >> 17) & (NODES_PER_BUCK - 1))], 1);
    }
    __syncthreads();
    if (tid < NODES_PER_BUCK) sc[tid] = cnt[tid];
    __syncthreads();
    for (int o = 1; o < NODES_PER_BUCK; o <<= 1) {
        int add = 0;
        if (tid < NODES_PER_BUCK && tid >= o) add = sc[tid - o];
        __syncthreads();
        if (tid < NODES_PER_BUCK) sc[tid] += add;
        __syncthreads();
    }
    if (tid < NODES_PER_BUCK) {
        int node = nodeLo + tid;
        int rs = startE + sc[tid] - cnt[tid];
        cur[tid] = rs;
        if (node < N_NODES) {
            rowStart[node] = rs;
            deg[node] = cnt[tid];
        }
    }
    __syncthreads();
    for (int i = startE + tid; i < endE; i += 1024) {
        ull rec = tmp[i];
        int dl  = (int)((rec >> 17) & (NODES_PER_BUCK - 1));
        int src = (int)(rec & 0x1FFFFULL);
        int val = (int)((rec >> 34) << 2);
        int pos = atomicAdd(&cur[dl], 1);
        sorted[pos] = make_int2(src, val);
    }
}

// ---- pull: one wave per dst node; lane = (edge-subgroup, dim-quad).
// float4 gathers (4 edges/instr) + prefetched next-iter edge records.
__global__ void pull_kernel(const float* __restrict__ A,
                            float* __restrict__ B,
                            float* __restrict__ acc,
                            const int2* __restrict__ sorted,
                            const int* __restrict__ rowStart,
                            const int* __restrict__ deg,
                            int writeB) {
    int t = blockIdx.x * blockDim.x + threadIdx.x;
    int node = t >> 6;
    if (node >= N_NODES) return;
    int lane = t & 63;
    int eg = lane >> 4;      // 0..3 edge subgroup
    int d4 = lane & 15;      // dim quad
    int start = rowStart[node];
    int cnt   = deg[node];   // wave-uniform
    const int2* ep = sorted + start;
    const float4* A4 = (const float4*)A;

    float4 a0 = make_float4(0.f,0.f,0.f,0.f), a1 = a0, a2 = a0, a3 = a0;
    int j = 0;
    if (cnt >= 16) {
        int2 r0 = ep[eg], r1 = ep[4 + eg], r2 = ep[8 + eg], r3 = ep[12 + eg];
        for (;;) {
            float4 g0 = A4[(((long long)r0.x) << 4) + d4];
            float4 g1 = A4[(((long long)r1.x) << 4) + d4];
            float4 g2 = A4[(((long long)r2.x) << 4) + d4];
            float4 g3 = A4[(((long long)r3.x) << 4) + d4];
            int nj = j + 16;
            bool more = (nj + 16 <= cnt);             // wave-uniform
            int2 q0, q1, q2, q3;
            if (more) {                               // prefetch next records
                q0 = ep[nj + eg];     q1 = ep[nj + 4 + eg];
                q2 = ep[nj + 8 + eg]; q3 = ep[nj + 12 + eg];
            }
            float w0 = __int_as_float(r0.y), w1 = __int_as_float(r1.y);
            float w2 = __int_as_float(r2.y), w3 = __int_as_float(r3.y);
            a0.x = fmaf(w0, g0.x, a0.x); a0.y = fmaf(w0, g0.y, a0.y);
            a0.z = fmaf(w0, g0.z, a0.z); a0.w = fmaf(w0, g0.w, a0.w);
            a1.x = fmaf(w1, g1.x, a1.x); a1.y = fmaf(w1, g1.y, a1.y);
            a1.z = fmaf(w1, g1.z, a1.z); a1.w = fmaf(w1, g1.w, a1.w);
            a2.x = fmaf(w2, g2.x, a2.x); a2.y = fmaf(w2, g2.y, a2.y);
            a2.z = fmaf(w2, g2.z, a2.z); a2.w = fmaf(w2, g2.w, a2.w);
            a3.x = fmaf(w3, g3.x, a3.x); a3.y = fmaf(w3, g3.y, a3.y);
            a3.z = fmaf(w3, g3.z, a3.z); a3.w = fmaf(w3, g3.w, a3.w);
            j = nj;
            if (!more) break;
            r0 = q0; r1 = q1; r2 = q2; r3 = q3;
        }
    }
    for (; j < cnt; j += 4) {
        int idx = j + eg;
        int2 e = (idx < cnt) ? ep[idx] : make_int2(0, 0);   // val bits 0 -> w = 0
        float4 g = A4[(((long long)e.x) << 4) + d4];
        float w = __int_as_float(e.y);
        a0.x = fmaf(w, g.x, a0.x); a0.y = fmaf(w, g.y, a0.y);
        a0.z = fmaf(w, g.z, a0.z); a0.w = fmaf(w, g.w, a0.w);
    }
    float4 s;
    s.x = (a0.x + a1.x) + (a2.x + a3.x);
    s.y = (a0.y + a1.y) + (a2.y + a3.y);
    s.z = (a0.z + a1.z) + (a2.z + a3.z);
    s.w = (a0.w + a1.w) + (a2.w + a3.w);
    s.x += __shfl_xor(s.x, 16, 64); s.y += __shfl_xor(s.y, 16, 64);
    s.z += __shfl_xor(s.z, 16, 64); s.w += __shfl_xor(s.w, 16, 64);
    s.x += __shfl_xor(s.x, 32, 64); s.y += __shfl_xor(s.y, 32, 64);
    s.z += __shfl_xor(s.z, 32, 64); s.w += __shfl_xor(s.w, 32, 64);
    if (eg == 0) {
        long long o = ((long long)node << 4) + d4;
        float4* B4 = (float4*)B;
        float4* C4 = (float4*)acc;
        float4 c = C4[o];
        c.x += s.x; c.y += s.y; c.z += s.z; c.w += s.w;
        if (writeB) B4[o] = s;
        C4[o] = c;
    }
}

// one wave per batch element: dot(acc[u], acc[NUM_USERS+i]) / 16
__global__ void dot_kernel(const float* __restrict__ acc,
                           const int* __restrict__ users,
                           const int* __restrict__ items,
                           float* __restrict__ out) {
    int t = blockIdx.x * blockDim.x + threadIdx.x;
    int b = t >> 6;
    int d = t & 63;
    if (b >= BATCH) return;
    int u  = users[b];
    int it = items[b] + NUM_USERS;
    float p = acc[(long long)u * EMB_DIM + d] * acc[(long long)it * EMB_DIM + d];
    #pragma unroll
    for (int off = 32; off >= 1; off >>= 1)
        p += __shfl_down(p, off, 64);
    if (d == 0) out[b] = p * 0.0625f;
}

extern "C" void kernel_launch(void* const* d_in, const int* in_sizes, int n_in,
                              void* d_out, int out_size, void* d_ws, size_t ws_size,
                              hipStream_t stream) {
    const float* user_emb = (const float*)d_in[0];
    const float* item_emb = (const float*)d_in[1];
    const float* edge_val = (const float*)d_in[2];
    const int*   edge_src = (const int*)d_in[3];
    const int*   edge_dst = (const int*)d_in[4];
    const int*   users    = (const int*)d_in[5];
    const int*   items    = (const int*)d_in[6];
    float* out = (float*)d_out;

    const size_t embBytes  = (size_t)N_NODES * EMB_DIM * sizeof(float);  // 25.6 MB
    const size_t edgeBytes = (size_t)NNZ * sizeof(int2);                 // 25.6 MB
    const size_t nodeBytes = (size_t)N_NODES * sizeof(int);              // 400 KB

    char* w = (char*)d_ws;
    float* bufA      = (float*)(w);   w += embBytes;
    float* bufB      = (float*)(w);   w += embBytes;   // = tmp (dst-partitioned)
    float* acc       = (float*)(w);   w += embBytes;   // = tmpS (src-partitioned)
    int2*  sorted    = (int2*)(w);    w += edgeBytes;
    int*   deg       = (int*)(w);     w += nodeBytes;
    int*   rowStart  = (int*)(w);     w += nodeBytes;
    int*   srcCnt    = (int*)(w);     w += NBUCK * sizeof(int);
    int*   dstCnt    = (int*)(w);     w += NBUCK * sizeof(int);
    int*   srcStart  = (int*)(w);     w += (NBUCK + 1) * sizeof(int);
    int*   dstStart  = (int*)(w);     w += (NBUCK + 1) * sizeof(int);
    int*   srcCursor = (int*)(w);     w += NBUCK * sizeof(int);
    int*   dstCursor = (int*)(w);     w += NBUCK * sizeof(int);

    ull* tmpS = (ull*)acc;   // consumed by partA before init_emb overwrites acc
    ull* tmp  = (ull*)bufB;  // consumed by partB before first pull writes bufB

    const int vecTotal   = N_NODES * (EMB_DIM / 4);
    const int initBlocks = (vecTotal + 255) / 256;
    const int tileBlocks = (NNZ + TILE_EDGES - 1) / TILE_EDGES;   // 391

    hipMemsetAsync(srcCnt, 0, 2 * NBUCK * sizeof(int), stream);   // srcCnt + dstCnt
    hist_src_kernel<<<tileBlocks, 256, 0, stream>>>(edge_src, srcCnt);
    scan512_kernel<<<1, NBUCK, 0, stream>>>(srcCnt, srcStart, srcCursor);
    srcPart_kernel<<<tileBlocks, 256, 0, stream>>>(edge_val, edge_src, edge_dst,
                                                   srcCursor, dstCnt, tmpS);
    scan512_kernel<<<1, NBUCK, 0, stream>>>(dstCnt, dstStart, dstCursor);
    partA_kernel<<<tileBlocks, 256, 0, stream>>>(tmpS, dstCursor, tmp);
    partB_kernel<<<NBUCK_BLOCKS, 1024, 0, stream>>>(tmp, dstStart, rowStart, deg, sorted);

    init_emb_kernel<<<initBlocks, 256, 0, stream>>>(user_emb, item_emb, bufA, acc);

    const int pullBlocks = (N_NODES * 64 + 255) / 256;
    for (int layer = 0; layer < N_LAYERS; ++layer) {
        pull_kernel<<<pullBlocks, 256, 0, stream>>>(bufA, bufB, acc, sorted, rowStart, deg,
                                                    layer < N_LAYERS - 1 ? 1 : 0);
        float* tswap = bufA; bufA = bufB; bufB = tswap;
    }

    const int dotBlocks = (BATCH * 64 + 255) / 256;
    dot_kernel<<<dotBlocks, 256, 0, stream>>>(acc, users, items, out);
}

// Round 7
// 427.029 us; speedup vs baseline: 1.4315x; 1.4315x over previous
//
#include <hip/hip_runtime.h>

#define NUM_USERS 50000
#define NUM_ITEMS 50000
#define N_NODES   100000
#define NNZ       3200000
#define EMB_DIM   64
#define N_LAYERS  3
#define BATCH     16384

#define NBUCK 512
#define ABITS 8                  // bucket = dst >> 8 (256 nodes/bucket, 391 used)
#define NODES_PER_BUCK 256
#define TILE_EDGES 8192
#define NBUCK_BLOCKS ((N_NODES + NODES_PER_BUCK - 1) / NODES_PER_BUCK)   // 391

typedef unsigned long long ull;

// ---- bf16 helpers (RNE) ----
__device__ inline unsigned bf16pair(float a, float b) {
    unsigned ua = __float_as_uint(a), ub = __float_as_uint(b);
    unsigned r0 = (ua + 0x7fffu + ((ua >> 16) & 1u)) >> 16;
    unsigned r1 = (ub + 0x7fffu + ((ub >> 16) & 1u)) >> 16;
    return r0 | (r1 << 16);
}

// accumulate 8 bf16 dims (one uint4) * w into s[0..7]
__device__ inline void acc8(float* s, uint4 g, float w) {
    s[0] = fmaf(w, __uint_as_float(g.x << 16),        s[0]);
    s[1] = fmaf(w, __uint_as_float(g.x & 0xffff0000u), s[1]);
    s[2] = fmaf(w, __uint_as_float(g.y << 16),        s[2]);
    s[3] = fmaf(w, __uint_as_float(g.y & 0xffff0000u), s[3]);
    s[4] = fmaf(w, __uint_as_float(g.z << 16),        s[4]);
    s[5] = fmaf(w, __uint_as_float(g.z & 0xffff0000u), s[5]);
    s[6] = fmaf(w, __uint_as_float(g.w << 16),        s[6]);
    s[7] = fmaf(w, __uint_as_float(g.w & 0xffff0000u), s[7]);
}

// init: acc(fp32) = concat(ue, ie); bufA16(bf16) = same, rounded
__global__ void init_emb_kernel(const float* __restrict__ ue,
                                const float* __restrict__ ie,
                                unsigned* __restrict__ bufA16,   // as uint2-granular
                                float* __restrict__ acc) {
    int idx = blockIdx.x * blockDim.x + threadIdx.x;   // per float4 (4 dims)
    const int total = N_NODES * (EMB_DIM / 4);
    if (idx >= total) return;
    const int uoff = NUM_USERS * (EMB_DIM / 4);
    float4 v;
    if (idx < uoff) v = ((const float4*)ue)[idx];
    else            v = ((const float4*)ie)[idx - uoff];
    ((float4*)acc)[idx] = v;
    uint2 h;
    h.x = bf16pair(v.x, v.y);
    h.y = bf16pair(v.z, v.w);
    ((uint2*)bufA16)[idx] = h;
}

// coarse 512-bucket histogram of dst>>8
__global__ void bucket_hist_kernel(const int* __restrict__ ed, int* __restrict__ bucketCnt) {
    __shared__ int h[NBUCK];
    int tid = threadIdx.x;
    int e0 = blockIdx.x * TILE_EDGES;
    for (int i = tid; i < NBUCK; i += 256) h[i] = 0;
    __syncthreads();
    for (int i = tid; i < TILE_EDGES; i += 256) {
        int e = e0 + i;
        if (e < NNZ) atomicAdd(&h[((unsigned)ed[e]) >> ABITS], 1);
    }
    __syncthreads();
    for (int i = tid; i < NBUCK; i += 256) {
        int c = h[i];
        if (c) atomicAdd(&bucketCnt[i], c);
    }
}

// single-block exclusive scan of 512 bucket counts
__global__ void bucket_scan_kernel(const int* __restrict__ bucketCnt,
                                   int* __restrict__ bucketStart,
                                   int* __restrict__ bucketCursor) {
    __shared__ int sm[NBUCK];
    int t = threadIdx.x;          // 512
    int v = bucketCnt[t];
    sm[t] = v;
    __syncthreads();
    for (int o = 1; o < NBUCK; o <<= 1) {
        int add = (t >= o) ? sm[t - o] : 0;
        __syncthreads();
        sm[t] += add;
        __syncthreads();
    }
    int excl = sm[t] - v;
    bucketStart[t]  = excl;
    bucketCursor[t] = excl;
    if (t == NBUCK - 1) bucketStart[NBUCK] = NNZ;
}

// pass A: partition edges into 512 coarse dst-buckets.
// rec = src(17) | dstLocal(8)<<17 in low32; full val bits in high32.
__global__ void partA_kernel(const float* __restrict__ ev,
                             const int*  __restrict__ es,
                             const int*  __restrict__ ed,
                             int* __restrict__ bucketCursor,
                             ull* __restrict__ tmp) {
    __shared__ int hist[NBUCK];
    __shared__ int base[NBUCK];
    __shared__ int cnt2[NBUCK];
    int tid = threadIdx.x;
    int e0 = blockIdx.x * TILE_EDGES;

    for (int i = tid; i < NBUCK; i += 256) hist[i] = 0;
    __syncthreads();
    for (int i = tid; i < TILE_EDGES; i += 256) {
        int e = e0 + i;
        if (e < NNZ) atomicAdd(&hist[((unsigned)ed[e]) >> ABITS], 1);
    }
    __syncthreads();
    for (int i = tid; i < NBUCK; i += 256) {
        int c = hist[i];
        base[i] = c ? atomicAdd(&bucketCursor[i], c) : 0;
        cnt2[i] = 0;
    }
    __syncthreads();
    for (int i = tid; i < TILE_EDGES; i += 256) {
        int e = e0 + i;
        if (e >= NNZ) continue;
        int dst = ed[e];
        int b = ((unsigned)dst) >> ABITS;
        int pos = base[b] + atomicAdd(&cnt2[b], 1);
        ull rec = (ull)(unsigned)(es[e] | ((dst & (NODES_PER_BUCK - 1)) << 17))
                | ((ull)(unsigned)__float_as_int(ev[e]) << 32);
        tmp[pos] = rec;
    }
}

// pass B: per bucket — node degrees + rowStart via LDS scan, then scatter to CSR
__global__ void partB_kernel(const ull* __restrict__ tmp,
                             const int* __restrict__ bucketStart,
                             int* __restrict__ rowStart,
                             int* __restrict__ deg,
                             int2* __restrict__ sorted) {
    __shared__ int cnt[NODES_PER_BUCK];
    __shared__ int sc[NODES_PER_BUCK];
    __shared__ int cur[NODES_PER_BUCK];
    int b = blockIdx.x;
    int tid = threadIdx.x;           // 1024
    int nodeLo = b << ABITS;
    int startE = bucketStart[b];
    int endE   = bucketStart[b + 1];

    if (tid < NODES_PER_BUCK) cnt[tid] = 0;
    __syncthreads();
    for (int i = startE + tid; i < endE; i += 1024) {
        ull rec = tmp[i];
        atomicAdd(&cnt[(int)((rec >> 17) & (NODES_PER_BUCK - 1))], 1);
    }
    __syncthreads();
    if (tid < NODES_PER_BUCK) sc[tid] = cnt[tid];
    __syncthreads();
    for (int o = 1; o < NODES_PER_BUCK; o <<= 1) {
        int add = 0;
        if (tid < NODES_PER_BUCK && tid >= o) add = sc[tid - o];
        __syncthreads();
        if (tid < NODES_PER_BUCK) sc[tid] += add;
        __syncthreads();
    }
    if (tid < NODES_PER_BUCK) {
        int node = nodeLo + tid;
        int rs = startE + sc[tid] - cnt[tid];
        cur[tid] = rs;
        if (node < N_NODES) {
            rowStart[node] = rs;
            deg[node] = cnt[tid];
        }
    }
    __syncthreads();
    for (int i = startE + tid; i < endE; i += 1024) {
        ull rec = tmp[i];
        int dl  = (int)((rec >> 17) & (NODES_PER_BUCK - 1));
        int src = (int)(rec & 0x1FFFFULL);
        int pos = atomicAdd(&cur[dl], 1);
        sorted[pos] = make_int2(src, (int)(rec >> 32));
    }
}

// ---- pull: one wave per dst node; lane = (edge-subgroup eg=lane>>3, dim-octet d8=lane&7).
// bf16 table: one uint4 gather = 8 dims of one edge; 8 edges per gather batch,
// 16 edges in flight with the 2-deep unroll. Accumulate fp32.
__global__ void pull_kernel(const uint4* __restrict__ A16,
                            uint4* __restrict__ B16,
                            float* __restrict__ acc,
                            const int2* __restrict__ sorted,
                            const int* __restrict__ rowStart,
                            const int* __restrict__ deg,
                            int writeB) {
    int t = blockIdx.x * blockDim.x + threadIdx.x;
    int node = t >> 6;
    if (node >= N_NODES) return;
    int lane = t & 63;
    int eg = lane >> 3;      // 0..7 edge subgroup
    int d8 = lane & 7;       // dim octet (8 bf16 dims = 16 B)
    int start = rowStart[node];
    int cnt   = deg[node];   // wave-uniform
    const int2* ep = sorted + start;

    float s[8] = {0.f,0.f,0.f,0.f,0.f,0.f,0.f,0.f};
    int j = 0;
    while (j + 16 <= cnt) {
        int2 r0 = ep[j + eg];
        int2 r1 = ep[j + 8 + eg];
        uint4 g0 = A16[(((long long)r0.x) << 3) + d8];
        uint4 g1 = A16[(((long long)r1.x) << 3) + d8];
        acc8(s, g0, __int_as_float(r0.y));
        acc8(s, g1, __int_as_float(r1.y));
        j += 16;
    }
    for (; j < cnt; j += 8) {
        int idx = j + eg;
        int2 e = (idx < cnt) ? ep[idx] : make_int2(0, 0);   // val bits 0 -> w = 0
        uint4 g = A16[(((long long)e.x) << 3) + d8];
        acc8(s, g, __int_as_float(e.y));
    }
    #pragma unroll
    for (int k = 0; k < 8; ++k) {
        s[k] += __shfl_xor(s[k], 8, 64);
        s[k] += __shfl_xor(s[k], 16, 64);
        s[k] += __shfl_xor(s[k], 32, 64);
    }
    if (eg == 0) {
        // lane d8 owns dims d8*8 .. d8*8+7
        float4* C4 = (float4*)acc;
        long long o = ((long long)node << 4) + d8 * 2;   // float4 index
        float4 c0 = C4[o], c1 = C4[o + 1];
        c0.x += s[0]; c0.y += s[1]; c0.z += s[2]; c0.w += s[3];
        c1.x += s[4]; c1.y += s[5]; c1.z += s[6]; c1.w += s[7];
        C4[o] = c0; C4[o + 1] = c1;
        if (writeB) {
            uint4 h;
            h.x = bf16pair(s[0], s[1]);
            h.y = bf16pair(s[2], s[3]);
            h.z = bf16pair(s[4], s[5]);
            h.w = bf16pair(s[6], s[7]);
            B16[(((long long)node) << 3) + d8] = h;
        }
    }
}

// one wave per batch element: dot(acc[u], acc[NUM_USERS+i]) / 16
__global__ void dot_kernel(const float* __restrict__ acc,
                           const int* __restrict__ users,
                           const int* __restrict__ items,
                           float* __restrict__ out) {
    int t = blockIdx.x * blockDim.x + threadIdx.x;
    int b = t >> 6;
    int d = t & 63;
    if (b >= BATCH) return;
    int u  = users[b];
    int it = items[b] + NUM_USERS;
    float p = acc[(long long)u * EMB_DIM + d] * acc[(long long)it * EMB_DIM + d];
    #pragma unroll
    for (int off = 32; off >= 1; off >>= 1)
        p += __shfl_down(p, off, 64);
    if (d == 0) out[b] = p * 0.0625f;
}

extern "C" void kernel_launch(void* const* d_in, const int* in_sizes, int n_in,
                              void* d_out, int out_size, void* d_ws, size_t ws_size,
                              hipStream_t stream) {
    const float* user_emb = (const float*)d_in[0];
    const float* item_emb = (const float*)d_in[1];
    const float* edge_val = (const float*)d_in[2];
    const int*   edge_src = (const int*)d_in[3];
    const int*   edge_dst = (const int*)d_in[4];
    const int*   users    = (const int*)d_in[5];
    const int*   items    = (const int*)d_in[6];
    float* out = (float*)d_out;

    const size_t emb16Bytes = (size_t)N_NODES * EMB_DIM * 2;             // 12.8 MB
    const size_t embBytes   = (size_t)N_NODES * EMB_DIM * sizeof(float); // 25.6 MB
    const size_t edgeBytes  = (size_t)NNZ * sizeof(int2);                // 25.6 MB
    const size_t tmpBytes   = (size_t)NNZ * sizeof(ull);                 // 25.6 MB
    const size_t nodeBytes  = (size_t)N_NODES * sizeof(int);             // 400 KB

    char* w = (char*)d_ws;
    uint4* bufA16       = (uint4*)(w);   w += emb16Bytes;
    uint4* bufB16       = (uint4*)(w);   w += emb16Bytes;
    float* acc          = (float*)(w);   w += embBytes;
    int2*  sorted       = (int2*)(w);    w += edgeBytes;
    ull*   tmp          = (ull*)(w);     w += tmpBytes;
    int*   deg          = (int*)(w);     w += nodeBytes;
    int*   rowStart     = (int*)(w);     w += nodeBytes;
    int*   bucketCnt    = (int*)(w);     w += NBUCK * sizeof(int);
    int*   bucketStart  = (int*)(w);     w += (NBUCK + 1) * sizeof(int);
    int*   bucketCursor = (int*)(w);     w += NBUCK * sizeof(int);

    const int vecTotal   = N_NODES * (EMB_DIM / 4);
    const int initBlocks = (vecTotal + 255) / 256;
    const int tileBlocks = (NNZ + TILE_EDGES - 1) / TILE_EDGES;   // 391

    init_emb_kernel<<<initBlocks, 256, 0, stream>>>(user_emb, item_emb,
                                                    (unsigned*)bufA16, acc);

    hipMemsetAsync(bucketCnt, 0, NBUCK * sizeof(int), stream);
    bucket_hist_kernel<<<tileBlocks, 256, 0, stream>>>(edge_dst, bucketCnt);
    bucket_scan_kernel<<<1, NBUCK, 0, stream>>>(bucketCnt, bucketStart, bucketCursor);
    partA_kernel<<<tileBlocks, 256, 0, stream>>>(edge_val, edge_src, edge_dst,
                                                 bucketCursor, tmp);
    partB_kernel<<<NBUCK_BLOCKS, 1024, 0, stream>>>(tmp, bucketStart, rowStart, deg, sorted);

    const int pullBlocks = (N_NODES * 64 + 255) / 256;
    for (int layer = 0; layer < N_LAYERS; ++layer) {
        pull_kernel<<<pullBlocks, 256, 0, stream>>>(bufA16, bufB16, acc, sorted,
                                                    rowStart, deg,
                                                    layer < N_LAYERS - 1 ? 1 : 0);
        uint4* tswap = bufA16; bufA16 = bufB16; bufB16 = tswap;
    }

    const int dotBlocks = (BATCH * 64 + 255) / 256;
    dot_kernel<<<dotBlocks, 256, 0, stream>>>(acc, users, items, out);
}

// Round 8
// 370.638 us; speedup vs baseline: 1.6493x; 1.1521x over previous
//
#include <hip/hip_runtime.h>

#define NUM_USERS 50000
#define NUM_ITEMS 50000
#define N_NODES   100000
#define NNZ       3200000
#define EMB_DIM   64
#define N_LAYERS  3
#define BATCH     16384

#define NBUCK 512
#define ABITS 8                  // bucket = dst >> 8 (256 nodes/bucket, 391 used)
#define NODES_PER_BUCK 256
#define TILE_EDGES 8192
#define NBUCK_BLOCKS ((N_NODES + NODES_PER_BUCK - 1) / NODES_PER_BUCK)   // 391

typedef unsigned long long ull;

// ---- bf16 helpers (RNE) ----
__device__ inline unsigned bf16pair(float a, float b) {
    unsigned ua = __float_as_uint(a), ub = __float_as_uint(b);
    unsigned r0 = (ua + 0x7fffu + ((ua >> 16) & 1u)) >> 16;
    unsigned r1 = (ub + 0x7fffu + ((ub >> 16) & 1u)) >> 16;
    return r0 | (r1 << 16);
}

// accumulate 8 bf16 dims (one uint4) * w into s[0..7]
__device__ inline void acc8(float* s, uint4 g, float w) {
    s[0] = fmaf(w, __uint_as_float(g.x << 16),        s[0]);
    s[1] = fmaf(w, __uint_as_float(g.x & 0xffff0000u), s[1]);
    s[2] = fmaf(w, __uint_as_float(g.y << 16),        s[2]);
    s[3] = fmaf(w, __uint_as_float(g.y & 0xffff0000u), s[3]);
    s[4] = fmaf(w, __uint_as_float(g.z << 16),        s[4]);
    s[5] = fmaf(w, __uint_as_float(g.z & 0xffff0000u), s[5]);
    s[6] = fmaf(w, __uint_as_float(g.w << 16),        s[6]);
    s[7] = fmaf(w, __uint_as_float(g.w & 0xffff0000u), s[7]);
}

// init: acc(fp32) = concat(ue, ie); bufA16(bf16) = same, rounded
__global__ void init_emb_kernel(const float* __restrict__ ue,
                                const float* __restrict__ ie,
                                unsigned* __restrict__ bufA16,
                                float* __restrict__ acc) {
    int idx = blockIdx.x * blockDim.x + threadIdx.x;   // per float4 (4 dims)
    const int total = N_NODES * (EMB_DIM / 4);
    if (idx >= total) return;
    const int uoff = NUM_USERS * (EMB_DIM / 4);
    float4 v;
    if (idx < uoff) v = ((const float4*)ue)[idx];
    else            v = ((const float4*)ie)[idx - uoff];
    ((float4*)acc)[idx] = v;
    uint2 h;
    h.x = bf16pair(v.x, v.y);
    h.y = bf16pair(v.z, v.w);
    ((uint2*)bufA16)[idx] = h;
}

// coarse 512-bucket histogram of dst>>8 — 1024 threads/block, 8 edges/thread
__global__ void bucket_hist_kernel(const int* __restrict__ ed, int* __restrict__ bucketCnt) {
    __shared__ int h[NBUCK];
    int tid = threadIdx.x;
    int e0 = blockIdx.x * TILE_EDGES;
    for (int i = tid; i < NBUCK; i += 1024) h[i] = 0;
    __syncthreads();
    #pragma unroll
    for (int k = 0; k < 8; ++k) {
        int e = e0 + k * 1024 + tid;
        if (e < NNZ) atomicAdd(&h[((unsigned)ed[e]) >> ABITS], 1);
    }
    __syncthreads();
    for (int i = tid; i < NBUCK; i += 1024) {
        int c = h[i];
        if (c) atomicAdd(&bucketCnt[i], c);
    }
}

// single-block exclusive scan of 512 bucket counts
__global__ void bucket_scan_kernel(const int* __restrict__ bucketCnt,
                                   int* __restrict__ bucketStart,
                                   int* __restrict__ bucketCursor) {
    __shared__ int sm[NBUCK];
    int t = threadIdx.x;          // 512
    int v = bucketCnt[t];
    sm[t] = v;
    __syncthreads();
    for (int o = 1; o < NBUCK; o <<= 1) {
        int add = (t >= o) ? sm[t - o] : 0;
        __syncthreads();
        sm[t] += add;
        __syncthreads();
    }
    int excl = sm[t] - v;
    bucketStart[t]  = excl;
    bucketCursor[t] = excl;
    if (t == NBUCK - 1) bucketStart[NBUCK] = NNZ;
}

// pass A: partition edges into 512 coarse dst-buckets. 1024 threads/block,
// 8 edges/thread register-cached (single read of es/ed/ev).
// rec = src(17) | dstLocal(8)<<17 in low32; full val bits in high32.
__global__ void partA_kernel(const float* __restrict__ ev,
                             const int*  __restrict__ es,
                             const int*  __restrict__ ed,
                             int* __restrict__ bucketCursor,
                             ull* __restrict__ tmp) {
    __shared__ int hist[NBUCK];
    __shared__ int base[NBUCK];
    __shared__ int cnt2[NBUCK];
    int tid = threadIdx.x;            // 1024
    int e0 = blockIdx.x * TILE_EDGES;

    int   mySrc[8], myDst[8];
    float myVal[8];

    for (int i = tid; i < NBUCK; i += 1024) hist[i] = 0;
    __syncthreads();

    #pragma unroll
    for (int k = 0; k < 8; ++k) {
        int e = e0 + k * 1024 + tid;
        if (e < NNZ) {
            mySrc[k] = es[e];
            myDst[k] = ed[e];
            myVal[k] = ev[e];
            atomicAdd(&hist[((unsigned)myDst[k]) >> ABITS], 1);
        } else {
            myDst[k] = -1;
        }
    }
    __syncthreads();

    for (int i = tid; i < NBUCK; i += 1024) {
        int c = hist[i];
        base[i] = c ? atomicAdd(&bucketCursor[i], c) : 0;
        cnt2[i] = 0;
    }
    __syncthreads();

    #pragma unroll
    for (int k = 0; k < 8; ++k) {
        int dst = myDst[k];
        if (dst < 0) continue;
        int b = ((unsigned)dst) >> ABITS;
        int pos = base[b] + atomicAdd(&cnt2[b], 1);
        ull rec = (ull)(unsigned)(mySrc[k] | ((dst & (NODES_PER_BUCK - 1)) << 17))
                | ((ull)(unsigned)__float_as_int(myVal[k]) << 32);
        tmp[pos] = rec;
    }
}

// pass B: per bucket — node degrees + rowStart via LDS scan, then scatter to CSR
__global__ void partB_kernel(const ull* __restrict__ tmp,
                             const int* __restrict__ bucketStart,
                             int* __restrict__ rowStart,
                             int* __restrict__ deg,
                             int2* __restrict__ sorted) {
    __shared__ int cnt[NODES_PER_BUCK];
    __shared__ int sc[NODES_PER_BUCK];
    __shared__ int cur[NODES_PER_BUCK];
    int b = blockIdx.x;
    int tid = threadIdx.x;           // 1024
    int nodeLo = b << ABITS;
    int startE = bucketStart[b];
    int endE   = bucketStart[b + 1];

    if (tid < NODES_PER_BUCK) cnt[tid] = 0;
    __syncthreads();
    for (int i = startE + tid; i < endE; i += 1024) {
        ull rec = tmp[i];
        atomicAdd(&cnt[(int)((rec >> 17) & (NODES_PER_BUCK - 1))], 1);
    }
    __syncthreads();
    if (tid < NODES_PER_BUCK) sc[tid] = cnt[tid];
    __syncthreads();
    for (int o = 1; o < NODES_PER_BUCK; o <<= 1) {
        int add = 0;
        if (tid < NODES_PER_BUCK && tid >= o) add = sc[tid - o];
        __syncthreads();
        if (tid < NODES_PER_BUCK) sc[tid] += add;
        __syncthreads();
    }
    if (tid < NODES_PER_BUCK) {
        int node = nodeLo + tid;
        int rs = startE + sc[tid] - cnt[tid];
        cur[tid] = rs;
        if (node < N_NODES) {
            rowStart[node] = rs;
            deg[node] = cnt[tid];
        }
    }
    __syncthreads();
    for (int i = startE + tid; i < endE; i += 1024) {
        ull rec = tmp[i];
        int dl  = (int)((rec >> 17) & (NODES_PER_BUCK - 1));
        int src = (int)(rec & 0x1FFFFULL);
        int pos = atomicAdd(&cur[dl], 1);
        sorted[pos] = make_int2(src, (int)(rec >> 32));
    }
}

// ---- pull: one wave per dst node; lane = (edge-subgroup eg=lane>>3, dim-octet d8=lane&7).
// bf16 table: one uint4 gather = 8 dims of one edge; 8 edges per gather batch,
// 16 edges in flight with the 2-deep unroll. Accumulate fp32.
__global__ void pull_kernel(const uint4* __restrict__ A16,
                            uint4* __restrict__ B16,
                            float* __restrict__ acc,
                            const int2* __restrict__ sorted,
                            const int* __restrict__ rowStart,
                            const int* __restrict__ deg,
                            int writeB) {
    int t = blockIdx.x * blockDim.x + threadIdx.x;
    int node = t >> 6;
    if (node >= N_NODES) return;
    int lane = t & 63;
    int eg = lane >> 3;      // 0..7 edge subgroup
    int d8 = lane & 7;       // dim octet (8 bf16 dims = 16 B)
    int start = rowStart[node];
    int cnt   = deg[node];   // wave-uniform
    const int2* ep = sorted + start;

    float s[8] = {0.f,0.f,0.f,0.f,0.f,0.f,0.f,0.f};
    int j = 0;
    while (j + 16 <= cnt) {
        int2 r0 = ep[j + eg];
        int2 r1 = ep[j + 8 + eg];
        uint4 g0 = A16[(((long long)r0.x) << 3) + d8];
        uint4 g1 = A16[(((long long)r1.x) << 3) + d8];
        acc8(s, g0, __int_as_float(r0.y));
        acc8(s, g1, __int_as_float(r1.y));
        j += 16;
    }
    for (; j < cnt; j += 8) {
        int idx = j + eg;
        int2 e = (idx < cnt) ? ep[idx] : make_int2(0, 0);   // val bits 0 -> w = 0
        uint4 g = A16[(((long long)e.x) << 3) + d8];
        acc8(s, g, __int_as_float(e.y));
    }
    #pragma unroll
    for (int k = 0; k < 8; ++k) {
        s[k] += __shfl_xor(s[k], 8, 64);
        s[k] += __shfl_xor(s[k], 16, 64);
        s[k] += __shfl_xor(s[k], 32, 64);
    }
    if (eg == 0) {
        float4* C4 = (float4*)acc;
        long long o = ((long long)node << 4) + d8 * 2;   // float4 index
        float4 c0 = C4[o], c1 = C4[o + 1];
        c0.x += s[0]; c0.y += s[1]; c0.z += s[2]; c0.w += s[3];
        c1.x += s[4]; c1.y += s[5]; c1.z += s[6]; c1.w += s[7];
        C4[o] = c0; C4[o + 1] = c1;
        if (writeB) {
            uint4 h;
            h.x = bf16pair(s[0], s[1]);
            h.y = bf16pair(s[2], s[3]);
            h.z = bf16pair(s[4], s[5]);
            h.w = bf16pair(s[6], s[7]);
            B16[(((long long)node) << 3) + d8] = h;
        }
    }
}

// one wave per batch element: dot(acc[u], acc[NUM_USERS+i]) / 16
__global__ void dot_kernel(const float* __restrict__ acc,
                           const int* __restrict__ users,
                           const int* __restrict__ items,
                           float* __restrict__ out) {
    int t = blockIdx.x * blockDim.x + threadIdx.x;
    int b = t >> 6;
    int d = t & 63;
    if (b >= BATCH) return;
    int u  = users[b];
    int it = items[b] + NUM_USERS;
    float p = acc[(long long)u * EMB_DIM + d] * acc[(long long)it * EMB_DIM + d];
    #pragma unroll
    for (int off = 32; off >= 1; off >>= 1)
        p += __shfl_down(p, off, 64);
    if (d == 0) out[b] = p * 0.0625f;
}

extern "C" void kernel_launch(void* const* d_in, const int* in_sizes, int n_in,
                              void* d_out, int out_size, void* d_ws, size_t ws_size,
                              hipStream_t stream) {
    const float* user_emb = (const float*)d_in[0];
    const float* item_emb = (const float*)d_in[1];
    const float* edge_val = (const float*)d_in[2];
    const int*   edge_src = (const int*)d_in[3];
    const int*   edge_dst = (const int*)d_in[4];
    const int*   users    = (const int*)d_in[5];
    const int*   items    = (const int*)d_in[6];
    float* out = (float*)d_out;

    const size_t emb16Bytes = (size_t)N_NODES * EMB_DIM * 2;             // 12.8 MB
    const size_t embBytes   = (size_t)N_NODES * EMB_DIM * sizeof(float); // 25.6 MB
    const size_t edgeBytes  = (size_t)NNZ * sizeof(int2);                // 25.6 MB
    const size_t tmpBytes   = (size_t)NNZ * sizeof(ull);                 // 25.6 MB
    const size_t nodeBytes  = (size_t)N_NODES * sizeof(int);             // 400 KB

    char* w = (char*)d_ws;
    uint4* bufA16       = (uint4*)(w);   w += emb16Bytes;
    uint4* bufB16       = (uint4*)(w);   w += emb16Bytes;
    float* acc          = (float*)(w);   w += embBytes;
    int2*  sorted       = (int2*)(w);    w += edgeBytes;
    ull*   tmp          = (ull*)(w);     w += tmpBytes;
    int*   deg          = (int*)(w);     w += nodeBytes;
    int*   rowStart     = (int*)(w);     w += nodeBytes;
    int*   bucketCnt    = (int*)(w);     w += NBUCK * sizeof(int);
    int*   bucketStart  = (int*)(w);     w += (NBUCK + 1) * sizeof(int);
    int*   bucketCursor = (int*)(w);     w += NBUCK * sizeof(int);

    const int vecTotal   = N_NODES * (EMB_DIM / 4);
    const int initBlocks = (vecTotal + 255) / 256;
    const int tileBlocks = (NNZ + TILE_EDGES - 1) / TILE_EDGES;   // 391

    init_emb_kernel<<<initBlocks, 256, 0, stream>>>(user_emb, item_emb,
                                                    (unsigned*)bufA16, acc);

    hipMemsetAsync(bucketCnt, 0, NBUCK * sizeof(int), stream);
    bucket_hist_kernel<<<tileBlocks, 1024, 0, stream>>>(edge_dst, bucketCnt);
    bucket_scan_kernel<<<1, NBUCK, 0, stream>>>(bucketCnt, bucketStart, bucketCursor);
    partA_kernel<<<tileBlocks, 1024, 0, stream>>>(edge_val, edge_src, edge_dst,
                                                  bucketCursor, tmp);
    partB_kernel<<<NBUCK_BLOCKS, 1024, 0, stream>>>(tmp, bucketStart, rowStart, deg, sorted);

    const int pullBlocks = (N_NODES * 64 + 255) / 256;
    for (int layer = 0; layer < N_LAYERS; ++layer) {
        pull_kernel<<<pullBlocks, 256, 0, stream>>>(bufA16, bufB16, acc, sorted,
                                                    rowStart, deg,
                                                    layer < N_LAYERS - 1 ? 1 : 0);
        uint4* tswap = bufA16; bufA16 = bufB16; bufB16 = tswap;
    }

    const int dotBlocks = (BATCH * 64 + 255) / 256;
    dot_kernel<<<dotBlocks, 256, 0, stream>>>(acc, users, items, out);
}

// Round 10
// 351.405 us; speedup vs baseline: 1.7395x; 1.0547x over previous
//
#include <hip/hip_runtime.h>

#define NUM_USERS 50000
#define NUM_ITEMS 50000
#define N_NODES   100000
#define NNZ       3200000
#define EMB_DIM   64
#define N_LAYERS  3
#define BATCH     16384

#define NBUCK 512
#define ABITS 8                  // bucket = dst >> 8 (256 nodes/bucket, 391 used)
#define NODES_PER_BUCK 256
#define TILE_EDGES 8192
#define NBUCK_BLOCKS ((N_NODES + NODES_PER_BUCK - 1) / NODES_PER_BUCK)   // 391

typedef unsigned long long ull;

// ---- bf16 helpers (RNE) ----
__device__ inline unsigned bf16pair(float a, float b) {
    unsigned ua = __float_as_uint(a), ub = __float_as_uint(b);
    unsigned r0 = (ua + 0x7fffu + ((ua >> 16) & 1u)) >> 16;
    unsigned r1 = (ub + 0x7fffu + ((ub >> 16) & 1u)) >> 16;
    return r0 | (r1 << 16);
}

// accumulate 8 bf16 dims (one uint4) * w into s[0..7]
__device__ inline void acc8(float* s, uint4 g, float w) {
    s[0] = fmaf(w, __uint_as_float(g.x << 16),        s[0]);
    s[1] = fmaf(w, __uint_as_float(g.x & 0xffff0000u), s[1]);
    s[2] = fmaf(w, __uint_as_float(g.y << 16),        s[2]);
    s[3] = fmaf(w, __uint_as_float(g.y & 0xffff0000u), s[3]);
    s[4] = fmaf(w, __uint_as_float(g.z << 16),        s[4]);
    s[5] = fmaf(w, __uint_as_float(g.z & 0xffff0000u), s[5]);
    s[6] = fmaf(w, __uint_as_float(g.w << 16),        s[6]);
    s[7] = fmaf(w, __uint_as_float(g.w & 0xffff0000u), s[7]);
}

// init: acc(fp32) = concat(ue, ie); bufA16(bf16) = same.
// Block 0 also zeroes ALL 512 bucketCnt entries (2 per thread — ws is 0xAA-poisoned).
__global__ void init_emb_kernel(const float* __restrict__ ue,
                                const float* __restrict__ ie,
                                unsigned* __restrict__ bufA16,
                                float* __restrict__ acc,
                                int* __restrict__ bucketCnt) {
    int idx = blockIdx.x * blockDim.x + threadIdx.x;   // per float4 (4 dims)
    if (blockIdx.x == 0 && threadIdx.x < 256) {
        bucketCnt[threadIdx.x]       = 0;
        bucketCnt[threadIdx.x + 256] = 0;
    }
    const int total = N_NODES * (EMB_DIM / 4);
    if (idx >= total) return;
    const int uoff = NUM_USERS * (EMB_DIM / 4);
    float4 v;
    if (idx < uoff) v = ((const float4*)ue)[idx];
    else            v = ((const float4*)ie)[idx - uoff];
    ((float4*)acc)[idx] = v;
    uint2 h;
    h.x = bf16pair(v.x, v.y);
    h.y = bf16pair(v.z, v.w);
    ((uint2*)bufA16)[idx] = h;
}

// coarse 512-bucket histogram of dst>>8 — 1024 threads/block, 8 edges/thread
__global__ void bucket_hist_kernel(const int* __restrict__ ed, int* __restrict__ bucketCnt) {
    __shared__ int h[NBUCK];
    int tid = threadIdx.x;
    int e0 = blockIdx.x * TILE_EDGES;
    for (int i = tid; i < NBUCK; i += 1024) h[i] = 0;
    __syncthreads();
    #pragma unroll
    for (int k = 0; k < 8; ++k) {
        int e = e0 + k * 1024 + tid;
        if (e < NNZ) atomicAdd(&h[((unsigned)ed[e]) >> ABITS], 1);
    }
    __syncthreads();
    for (int i = tid; i < NBUCK; i += 1024) {
        int c = h[i];
        if (c) atomicAdd(&bucketCnt[i], c);
    }
}

// single-block exclusive scan of 512 bucket counts
__global__ void bucket_scan_kernel(const int* __restrict__ bucketCnt,
                                   int* __restrict__ bucketStart,
                                   int* __restrict__ bucketCursor) {
    __shared__ int sm[NBUCK];
    int t = threadIdx.x;          // 512
    int v = bucketCnt[t];
    sm[t] = v;
    __syncthreads();
    for (int o = 1; o < NBUCK; o <<= 1) {
        int add = (t >= o) ? sm[t - o] : 0;
        __syncthreads();
        sm[t] += add;
        __syncthreads();
    }
    int excl = sm[t] - v;
    bucketStart[t]  = excl;
    bucketCursor[t] = excl;
    if (t == NBUCK - 1) bucketStart[NBUCK] = NNZ;
}

// pass A: partition edges into 512 coarse dst-buckets. 1024 threads, 8 edges/thread.
// tmp rec: src(17) | dstLocal(8)<<17 | fix15(val)<<25   (40 bits used)
__global__ void partA_kernel(const float* __restrict__ ev,
                             const int*  __restrict__ es,
                             const int*  __restrict__ ed,
                             int* __restrict__ bucketCursor,
                             ull* __restrict__ tmp) {
    __shared__ int hist[NBUCK];
    __shared__ int base[NBUCK];
    __shared__ int cnt2[NBUCK];
    int tid = threadIdx.x;            // 1024
    int e0 = blockIdx.x * TILE_EDGES;

    int      mySrc[8], myDst[8];
    unsigned myQ[8];

    for (int i = tid; i < NBUCK; i += 1024) hist[i] = 0;
    __syncthreads();

    #pragma unroll
    for (int k = 0; k < 8; ++k) {
        int e = e0 + k * 1024 + tid;
        if (e < NNZ) {
            mySrc[k] = es[e];
            myDst[k] = ed[e];
            myQ[k]   = (unsigned)fminf(ev[e] * 32768.f + 0.5f, 32767.f);
            atomicAdd(&hist[((unsigned)myDst[k]) >> ABITS], 1);
        } else {
            myDst[k] = -1;
        }
    }
    __syncthreads();

    for (int i = tid; i < NBUCK; i += 1024) {
        int c = hist[i];
        base[i] = c ? atomicAdd(&bucketCursor[i], c) : 0;
        cnt2[i] = 0;
    }
    __syncthreads();

    #pragma unroll
    for (int k = 0; k < 8; ++k) {
        int dst = myDst[k];
        if (dst < 0) continue;
        int b = ((unsigned)dst) >> ABITS;
        int pos = base[b] + atomicAdd(&cnt2[b], 1);
        ull rec = (ull)(unsigned)(mySrc[k] | ((dst & (NODES_PER_BUCK - 1)) << 17))
                | ((ull)myQ[k] << 25);
        tmp[pos] = rec;
    }
}

// pass B: per bucket — node degrees + rowStart via LDS scan, then scatter to CSR.
// sorted rec (u32): src(17) | fix15(val)<<17
__global__ void partB_kernel(const ull* __restrict__ tmp,
                             const int* __restrict__ bucketStart,
                             int* __restrict__ rowStart,
                             int* __restrict__ deg,
                             unsigned* __restrict__ sorted) {
    __shared__ int cnt[NODES_PER_BUCK];
    __shared__ int sc[NODES_PER_BUCK];
    __shared__ int cur[NODES_PER_BUCK];
    int b = blockIdx.x;
    int tid = threadIdx.x;           // 1024
    int nodeLo = b << ABITS;
    int startE = bucketStart[b];
    int endE   = bucketStart[b + 1];

    if (tid < NODES_PER_BUCK) cnt[tid] = 0;
    __syncthreads();
    for (int i = startE + tid; i < endE; i += 1024) {
        ull rec = tmp[i];
        atomicAdd(&cnt[(int)((rec >> 17) & (NODES_PER_BUCK - 1))], 1);
    }
    __syncthreads();
    if (tid < NODES_PER_BUCK) sc[tid] = cnt[tid];
    __syncthreads();
    for (int o = 1; o < NODES_PER_BUCK; o <<= 1) {
        int add = 0;
        if (tid < NODES_PER_BUCK && tid >= o) add = sc[tid - o];
        __syncthreads();
        if (tid < NODES_PER_BUCK) sc[tid] += add;
        __syncthreads();
    }
    if (tid < NODES_PER_BUCK) {
        int node = nodeLo + tid;
        int rs = startE + sc[tid] - cnt[tid];
        cur[tid] = rs;
        if (node < N_NODES) {
            rowStart[node] = rs;
            deg[node] = cnt[tid];
        }
    }
    __syncthreads();
    for (int i = startE + tid; i < endE; i += 1024) {
        ull rec = tmp[i];
        int dl = (int)((rec >> 17) & (NODES_PER_BUCK - 1));
        unsigned o = (unsigned)(rec & 0x1FFFFULL) | ((unsigned)((rec >> 25) & 0x7FFF) << 17);
        int pos = atomicAdd(&cur[dl], 1);
        sorted[pos] = o;
    }
}

// ---- pull: one wave per dst node; lane = (eg=lane>>3 edge subgroup, d8=lane&7 dim octet).
// u32 edge records; uint4 bf16 gathers; 32 edges in flight (4 batches of 8).
__global__ void pull_kernel(const uint4* __restrict__ A16,
                            uint4* __restrict__ B16,
                            float* __restrict__ acc,
                            const unsigned* __restrict__ sorted,
                            const int* __restrict__ rowStart,
                            const int* __restrict__ deg,
                            int writeB) {
    int t = blockIdx.x * blockDim.x + threadIdx.x;
    int node = t >> 6;
    if (node >= N_NODES) return;
    int lane = t & 63;
    int eg = lane >> 3;      // 0..7
    int d8 = lane & 7;       // dim octet (16 B)
    int start = rowStart[node];
    int cnt   = deg[node];   // wave-uniform
    const unsigned* ep = sorted + start;
    const float k15 = 1.f / 32768.f;

    float s[8] = {0.f,0.f,0.f,0.f,0.f,0.f,0.f,0.f};
    int j = 0;
    while (j + 32 <= cnt) {
        unsigned r0 = ep[j + eg], r1 = ep[j + 8 + eg];
        unsigned r2 = ep[j + 16 + eg], r3 = ep[j + 24 + eg];
        uint4 g0 = A16[(((long long)(r0 & 0x1FFFFu)) << 3) + d8];
        uint4 g1 = A16[(((long long)(r1 & 0x1FFFFu)) << 3) + d8];
        uint4 g2 = A16[(((long long)(r2 & 0x1FFFFu)) << 3) + d8];
        uint4 g3 = A16[(((long long)(r3 & 0x1FFFFu)) << 3) + d8];
        acc8(s, g0, (float)(r0 >> 17) * k15);
        acc8(s, g1, (float)(r1 >> 17) * k15);
        acc8(s, g2, (float)(r2 >> 17) * k15);
        acc8(s, g3, (float)(r3 >> 17) * k15);
        j += 32;
    }
    while (j + 16 <= cnt) {
        unsigned r0 = ep[j + eg], r1 = ep[j + 8 + eg];
        uint4 g0 = A16[(((long long)(r0 & 0x1FFFFu)) << 3) + d8];
        uint4 g1 = A16[(((long long)(r1 & 0x1FFFFu)) << 3) + d8];
        acc8(s, g0, (float)(r0 >> 17) * k15);
        acc8(s, g1, (float)(r1 >> 17) * k15);
        j += 16;
    }
    for (; j < cnt; j += 8) {
        int idx = j + eg;
        unsigned r = (idx < cnt) ? ep[idx] : 0u;   // r=0 -> w=0
        uint4 g = A16[(((long long)(r & 0x1FFFFu)) << 3) + d8];
        acc8(s, g, (float)(r >> 17) * k15);
    }
    #pragma unroll
    for (int k = 0; k < 8; ++k) {
        s[k] += __shfl_xor(s[k], 8, 64);
        s[k] += __shfl_xor(s[k], 16, 64);
        s[k] += __shfl_xor(s[k], 32, 64);
    }
    if (eg == 0) {
        float4* C4 = (float4*)acc;
        long long o = ((long long)node << 4) + d8 * 2;
        float4 c0 = C4[o], c1 = C4[o + 1];
        c0.x += s[0]; c0.y += s[1]; c0.z += s[2]; c0.w += s[3];
        c1.x += s[4]; c1.y += s[5]; c1.z += s[6]; c1.w += s[7];
        C4[o] = c0; C4[o + 1] = c1;
        if (writeB) {
            uint4 h;
            h.x = bf16pair(s[0], s[1]);
            h.y = bf16pair(s[2], s[3]);
            h.z = bf16pair(s[4], s[5]);
            h.w = bf16pair(s[6], s[7]);
            B16[(((long long)node) << 3) + d8] = h;
        }
    }
}

// one wave per batch element: dot(acc[u], acc[NUM_USERS+i]) / 16
__global__ void dot_kernel(const float* __restrict__ acc,
                           const int* __restrict__ users,
                           const int* __restrict__ items,
                           float* __restrict__ out) {
    int t = blockIdx.x * blockDim.x + threadIdx.x;
    int b = t >> 6;
    int d = t & 63;
    if (b >= BATCH) return;
    int u  = users[b];
    int it = items[b] + NUM_USERS;
    float p = acc[(long long)u * EMB_DIM + d] * acc[(long long)it * EMB_DIM + d];
    #pragma unroll
    for (int off = 32; off >= 1; off >>= 1)
        p += __shfl_down(p, off, 64);
    if (d == 0) out[b] = p * 0.0625f;
}

extern "C" void kernel_launch(void* const* d_in, const int* in_sizes, int n_in,
                              void* d_out, int out_size, void* d_ws, size_t ws_size,
                              hipStream_t stream) {
    const float* user_emb = (const float*)d_in[0];
    const float* item_emb = (const float*)d_in[1];
    const float* edge_val = (const float*)d_in[2];
    const int*   edge_src = (const int*)d_in[3];
    const int*   edge_dst = (const int*)d_in[4];
    const int*   users    = (const int*)d_in[5];
    const int*   items    = (const int*)d_in[6];
    float* out = (float*)d_out;

    const size_t emb16Bytes = (size_t)N_NODES * EMB_DIM * 2;             // 12.8 MB
    const size_t embBytes   = (size_t)N_NODES * EMB_DIM * sizeof(float); // 25.6 MB
    const size_t sortBytes  = (size_t)NNZ * sizeof(unsigned);            // 12.8 MB
    const size_t tmpBytes   = (size_t)NNZ * sizeof(ull);                 // 25.6 MB
    const size_t nodeBytes  = (size_t)N_NODES * sizeof(int);             // 400 KB

    char* w = (char*)d_ws;
    uint4*    bufA16       = (uint4*)(w);    w += emb16Bytes;
    uint4*    bufB16       = (uint4*)(w);    w += emb16Bytes;
    float*    acc          = (float*)(w);    w += embBytes;
    unsigned* sorted       = (unsigned*)(w); w += sortBytes;
    ull*      tmp          = (ull*)(w);      w += tmpBytes;
    int*      deg          = (int*)(w);      w += nodeBytes;
    int*      rowStart     = (int*)(w);      w += nodeBytes;
    int*      bucketCnt    = (int*)(w);      w += NBUCK * sizeof(int);
    int*      bucketStart  = (int*)(w);      w += (NBUCK + 1) * sizeof(int);
    int*      bucketCursor = (int*)(w);      w += NBUCK * sizeof(int);

    const int vecTotal   = N_NODES * (EMB_DIM / 4);
    const int initBlocks = (vecTotal + 255) / 256;
    const int tileBlocks = (NNZ + TILE_EDGES - 1) / TILE_EDGES;   // 391

    init_emb_kernel<<<initBlocks, 256, 0, stream>>>(user_emb, item_emb,
                                                    (unsigned*)bufA16, acc, bucketCnt);

    bucket_hist_kernel<<<tileBlocks, 1024, 0, stream>>>(edge_dst, bucketCnt);
    bucket_scan_kernel<<<1, NBUCK, 0, stream>>>(bucketCnt, bucketStart, bucketCursor);
    partA_kernel<<<tileBlocks, 1024, 0, stream>>>(edge_val, edge_src, edge_dst,
                                                  bucketCursor, tmp);
    partB_kernel<<<NBUCK_BLOCKS, 1024, 0, stream>>>(tmp, bucketStart, rowStart, deg, sorted);

    const int pullBlocks = (N_NODES * 64 + 255) / 256;
    for (int layer = 0; layer < N_LAYERS; ++layer) {
        pull_kernel<<<pullBlocks, 256, 0, stream>>>(bufA16, bufB16, acc, sorted,
                                                    rowStart, deg,
                                                    layer < N_LAYERS - 1 ? 1 : 0);
        uint4* tswap = bufA16; bufA16 = bufB16; bufB16 = tswap;
    }

    const int dotBlocks = (BATCH * 64 + 255) / 256;
    dot_kernel<<<dotBlocks, 256, 0, stream>>>(acc, users, items, out);
}